// Round 7
// baseline (418.721 us; speedup 1.0000x reference)
//
#include <hip/hip_runtime.h>
#include <hip/hip_bf16.h>

// Cross-modal gated channel-attention, B=16, C=256, HW=4096, 4 heads.
// Device I/O is FP32 (per reference dtypes); internal math bf16 MFMA.
// G = A·B^T per batch (256x256); logits = s·Wq·G(^T)·Wk^T;
// E = Wproj·diag(g)·blockdiag(attn_h·Wv_h);  out = X_res + E·X_kv.

#define BB 16
#define CC 256
#define HWN 4096

typedef __attribute__((ext_vector_type(8))) short bf8_t;   // 8 bf16 (4 VGPR)
typedef __attribute__((ext_vector_type(4))) float f4_t;
typedef unsigned short u16;
typedef unsigned int u32;

__device__ __forceinline__ float bf2f(u16 u) {
    union { float f; u32 i; } x; x.i = ((u32)u) << 16; return x.f;
}
__device__ __forceinline__ u16 f2bf(float f) {
    union { float f; u32 i; } x; x.f = f;
    u32 r = x.i + 0x7FFFu + ((x.i >> 16) & 1u);
    return (u16)(r >> 16);
}
__device__ __forceinline__ u32 pk2(float a, float b) {
    return (u32)f2bf(a) | ((u32)f2bf(b) << 16);
}
__device__ __forceinline__ bf8_t ld8(const u16* p) {
    return *reinterpret_cast<const bf8_t*>(p);
}
__device__ __forceinline__ bf8_t cvt8(float4 a, float4 b) {
    bf8_t r;
    r[0]=(short)f2bf(a.x); r[1]=(short)f2bf(a.y); r[2]=(short)f2bf(a.z); r[3]=(short)f2bf(a.w);
    r[4]=(short)f2bf(b.x); r[5]=(short)f2bf(b.y); r[6]=(short)f2bf(b.z); r[7]=(short)f2bf(b.w);
    return r;
}

// ---------------- K1: Gram partials (G = A·B^T, bf16 MFMA) + channel means ----------------
// grid: 128 gram wgs (b x it x jt x kc) + 128 mean wgs, block 512
__global__ __launch_bounds__(512) void k1(const float* __restrict__ A, const float* __restrict__ B,
                                          float* __restrict__ Gpart, float* __restrict__ pooled)
{
    const int tid = threadIdx.x;
    const int lane = tid & 63, wv = tid >> 6;
    const int ln15 = lane & 15, gq = lane >> 4, g8 = gq * 8;
    const int wg = blockIdx.x;
    if (wg < 128) {
        const int kc = wg & 1, jt = (wg >> 1) & 1, it = (wg >> 2) & 1, b = wg >> 3;
        __shared__ alignas(16) u16 lA[128][72];   // +8 pad
        __shared__ alignas(16) u16 lB[128][72];
        const float* Ab  = A + (size_t)(b * CC + it * 128) * HWN + kc * 2048;
        const float* Bbp = B + (size_t)(b * CC + jt * 128) * HWN + kc * 2048;
        f4_t acc[4][2];
        #pragma unroll
        for (int i = 0; i < 4; ++i)
            #pragma unroll
            for (int j = 0; j < 2; ++j) acc[i][j] = (f4_t){0.f,0.f,0.f,0.f};
        const int wm = wv >> 2, wn = wv & 3;
        for (int k0 = 0; k0 < 2048; k0 += 64) {
            #pragma unroll
            for (int m = 0; m < 2; ++m) {
                int idx = m * 512 + tid;
                int row = idx >> 3, cc8 = (idx & 7) * 8;
                const float* pa = Ab + (size_t)row * HWN + k0 + cc8;
                float4 a0 = *reinterpret_cast<const float4*>(pa);
                float4 a1 = *reinterpret_cast<const float4*>(pa + 4);
                *reinterpret_cast<bf8_t*>(&lA[row][cc8]) = cvt8(a0, a1);
                const float* pb = Bbp + (size_t)row * HWN + k0 + cc8;
                float4 b0 = *reinterpret_cast<const float4*>(pb);
                float4 b1 = *reinterpret_cast<const float4*>(pb + 4);
                *reinterpret_cast<bf8_t*>(&lB[row][cc8]) = cvt8(b0, b1);
            }
            __syncthreads();
            #pragma unroll
            for (int ks = 0; ks < 2; ++ks) {
                bf8_t af[4], bfr[2];
                #pragma unroll
                for (int i = 0; i < 4; ++i)
                    af[i] = *reinterpret_cast<bf8_t*>(&lA[wm*64 + i*16 + ln15][ks*32 + g8]);
                #pragma unroll
                for (int j = 0; j < 2; ++j)
                    bfr[j] = *reinterpret_cast<bf8_t*>(&lB[wn*32 + j*16 + ln15][ks*32 + g8]);
                #pragma unroll
                for (int i = 0; i < 4; ++i)
                    #pragma unroll
                    for (int j = 0; j < 2; ++j)
                        acc[i][j] = __builtin_amdgcn_mfma_f32_16x16x32_bf16(af[i], bfr[j], acc[i][j], 0, 0, 0);
            }
            __syncthreads();
        }
        float* Gp = Gpart + ((size_t)kc * BB + b) * CC * CC;
        #pragma unroll
        for (int i = 0; i < 4; ++i) {
            int row0 = it * 128 + wm * 64 + i * 16 + gq * 4;
            #pragma unroll
            for (int j = 0; j < 2; ++j) {
                int col = jt * 128 + wn * 32 + j * 16 + ln15;
                #pragma unroll
                for (int r = 0; r < 4; ++r)
                    Gp[(size_t)(row0 + r) * CC + col] = acc[i][j][r];
            }
        }
    } else {
        // channel means (fp32): wg -> (b, A-or-B, 64-row chunk); wave handles 8 rows
        const int id = wg - 128;
        const int b = id >> 3, half = (id >> 2) & 1, ch = id & 3;
        const float* S = (half ? B : A) + (size_t)b * CC * HWN;
        for (int rr = 0; rr < 8; ++rr) {
            int row = ch * 64 + wv * 8 + rr;
            const float* rp = S + (size_t)row * HWN;
            float s = 0.f;
            for (int itx = 0; itx < 16; ++itx) {
                float4 v = *reinterpret_cast<const float4*>(rp + itx * 256 + lane * 4);
                s += v.x + v.y + v.z + v.w;
            }
            #pragma unroll
            for (int off = 32; off > 0; off >>= 1) s += __shfl_down(s, off, 64);
            if (lane == 0) pooled[b * 512 + half * 256 + row] = s * (1.f / HWN);
        }
    }
}

// ---------------- K2: reduce G -> G/G^T bf16; gate MLP; Wv^T; weight bf16 copies ----------------
// grid: 16 gate + 64 G-finalize + 2 WvT + 6 wconv = 88, block 256
__global__ __launch_bounds__(256) void k2(const float* __restrict__ Gpart,
    const float* __restrict__ pooled,
    const float* __restrict__ wg1, const float* __restrict__ bg1,
    const float* __restrict__ wg2, const float* __restrict__ bg2,
    const float* __restrict__ wvA, const float* __restrict__ wvB,
    const float* __restrict__ wqA, const float* __restrict__ wqB,
    const float* __restrict__ wkA, const float* __restrict__ wkB,
    const float* __restrict__ wprojA, const float* __restrict__ wprojB,
    u16* __restrict__ Gb, u16* __restrict__ GTb,
    float* __restrict__ gate, u16* __restrict__ WvAT, u16* __restrict__ WvBT,
    u16* __restrict__ w16)
{
    const int tid = threadIdx.x, wg = blockIdx.x;
    if (wg < 16) {
        const int b = wg;
        __shared__ float h1[64];
        if (tid < 64) {
            float s = bg1[tid];
            const float* wr = wg1 + tid * 512;
            const float* pl = pooled + b * 512;
            for (int j = 0; j < 512; ++j) s += pl[j] * wr[j];
            h1[tid] = fmaxf(s, 0.f);
        }
        __syncthreads();
        float s = bg2[tid];
        const float* wr = wg2 + tid * 64;
        #pragma unroll
        for (int j = 0; j < 64; ++j) s += h1[j] * wr[j];
        gate[b * 256 + tid] = 1.f / (1.f + expf(-s));
    } else if (wg < 80) {
        const int id = wg - 16, b = id >> 2, rc = id & 3;
        const float* P0 = Gpart + (size_t)b * CC * CC;
        const float* P1 = Gpart + ((size_t)BB + b) * CC * CC;
        for (int i = 0; i < 64; ++i) {
            int idx = i * 256 + tid;
            int r = rc * 64 + (idx >> 8), c = idx & 255;
            size_t o = (size_t)r * CC + c;
            Gb[(size_t)b * CC * CC + o] = f2bf(P0[o] + P1[o]);
        }
        for (int i = 0; i < 64; ++i) {
            int idx = i * 256 + tid;
            int r = rc * 64 + (idx & 63), c = idx >> 6;
            float v = P0[(size_t)r * CC + c] + P1[(size_t)r * CC + c];
            GTb[(size_t)b * CC * CC + (size_t)c * CC + r] = f2bf(v);
        }
    } else if (wg < 82) {
        const float* W = (wg == 80) ? wvA : wvB;
        u16* WT = (wg == 80) ? WvAT : WvBT;
        for (int i = 0; i < 256; ++i)
            WT[i * 256 + tid] = f2bf(W[tid * 256 + i]);
    } else {
        // weight fp32 -> bf16 copies: order [wqA, wqB, wkA, wkB, wprojA, wprojB]
        const int m = wg - 82;
        const float* W = (m == 0) ? wqA : (m == 1) ? wqB : (m == 2) ? wkA
                       : (m == 3) ? wkB : (m == 4) ? wprojA : wprojB;
        u16* D = w16 + (size_t)m * 65536;
        for (int i = 0; i < 128; ++i) {
            int e = (i * 256 + tid) * 2;
            float2 v = *reinterpret_cast<const float2*>(W + e);
            *reinterpret_cast<u32*>(D + e) = pk2(v.x, v.y);
        }
    }
}

// ---------------- K3: logits -> softmax -> T^T (gate folded) ----------------
// grid: 128 = b x dir x head, block 256 (4 waves)
__global__ __launch_bounds__(256) void k3(
    const u16* __restrict__ w16,
    const u16* __restrict__ Gb, const u16* __restrict__ GTb,
    const u16* __restrict__ WvAT, const u16* __restrict__ WvBT,
    const float* __restrict__ gate, u16* __restrict__ TgT)
{
    const int tid = threadIdx.x;
    const int lane = tid & 63, wv = tid >> 6;
    const int ln15 = lane & 15, gq = lane >> 4, g8 = gq * 8;
    const int id = blockIdx.x;
    const int h = id & 3, dir = (id >> 2) & 1, b = id >> 3;
    const u16* Wq  = w16 + (size_t)(dir ? 1 : 0) * 65536;   // dir0: wqA, dir1: wqB
    const u16* Wk  = w16 + (size_t)(dir ? 2 : 3) * 65536;   // dir0: wkB, dir1: wkA
    const u16* WvT = dir ? WvAT : WvBT;
    // stage1 B-operand must be M^T row-major; dir0 M=G -> GTb, dir1 M=G^T -> Gb
    const u16* Mop = (dir ? Gb : GTb) + (size_t)b * CC * CC;

    __shared__ alignas(16) u16 R1[64][264];
    __shared__ alignas(16) u16 attnS[64][72];

    // stage1: R1[cq][j] = sum_i Wq[h64+cq][i] * M[i][j]
    {
        f4_t acc[4][4];
        #pragma unroll
        for (int i=0;i<4;++i) { acc[i][0]=(f4_t){0,0,0,0}; acc[i][1]=(f4_t){0,0,0,0}; acc[i][2]=(f4_t){0,0,0,0}; acc[i][3]=(f4_t){0,0,0,0}; }
        for (int k0 = 0; k0 < 256; k0 += 32) {
            bf8_t a[4], bb[4];
            #pragma unroll
            for (int i = 0; i < 4; ++i)
                a[i] = ld8(Wq + (size_t)(h*64 + i*16 + ln15) * CC + k0 + g8);
            #pragma unroll
            for (int j = 0; j < 4; ++j)
                bb[j] = ld8(Mop + (size_t)(wv*64 + j*16 + ln15) * CC + k0 + g8);
            #pragma unroll
            for (int i = 0; i < 4; ++i)
                #pragma unroll
                for (int j = 0; j < 4; ++j)
                    acc[i][j] = __builtin_amdgcn_mfma_f32_16x16x32_bf16(a[i], bb[j], acc[i][j], 0,0,0);
        }
        #pragma unroll
        for (int i = 0; i < 4; ++i)
            #pragma unroll
            for (int j = 0; j < 4; ++j)
                #pragma unroll
                for (int r = 0; r < 4; ++r)
                    R1[i*16 + gq*4 + r][wv*64 + j*16 + ln15] = f2bf(acc[i][j][r]);
    }
    __syncthreads();
    // stage2: L = R1 · Wk_h^T, then softmax over 64 cols
    {
        f4_t accL[4];
        #pragma unroll
        for (int n = 0; n < 4; ++n) accL[n] = (f4_t){0,0,0,0};
        for (int k0 = 0; k0 < 256; k0 += 32) {
            bf8_t a = *reinterpret_cast<bf8_t*>(&R1[wv*16 + ln15][k0 + g8]);
            #pragma unroll
            for (int n = 0; n < 4; ++n) {
                bf8_t bb = ld8(Wk + (size_t)(h*64 + n*16 + ln15) * CC + k0 + g8);
                accL[n] = __builtin_amdgcn_mfma_f32_16x16x32_bf16(a, bb, accL[n], 0,0,0);
            }
        }
        #pragma unroll
        for (int r = 0; r < 4; ++r) {
            float v0 = accL[0][r]*0.125f, v1 = accL[1][r]*0.125f;
            float v2 = accL[2][r]*0.125f, v3 = accL[3][r]*0.125f;
            float mx = fmaxf(fmaxf(v0,v1), fmaxf(v2,v3));
            #pragma unroll
            for (int m = 1; m < 16; m <<= 1) mx = fmaxf(mx, __shfl_xor(mx, m, 64));
            float e0 = expf(v0-mx), e1 = expf(v1-mx), e2 = expf(v2-mx), e3 = expf(v3-mx);
            float s = e0+e1+e2+e3;
            #pragma unroll
            for (int m = 1; m < 16; m <<= 1) s += __shfl_xor(s, m, 64);
            float inv = 1.f / s;
            int row = wv*16 + gq*4 + r;
            attnS[row][ 0 + ln15] = f2bf(e0*inv);
            attnS[row][16 + ln15] = f2bf(e1*inv);
            attnS[row][32 + ln15] = f2bf(e2*inv);
            attnS[row][48 + ln15] = f2bf(e3*inv);
        }
    }
    __syncthreads();
    // stage3: T = attn · Wv_h (via WvT), fold gate, write T^T[c][h64+cv]
    {
        f4_t accT[4][4];
        #pragma unroll
        for (int i=0;i<4;++i) { accT[i][0]=(f4_t){0,0,0,0}; accT[i][1]=(f4_t){0,0,0,0}; accT[i][2]=(f4_t){0,0,0,0}; accT[i][3]=(f4_t){0,0,0,0}; }
        #pragma unroll
        for (int k0 = 0; k0 < 64; k0 += 32) {
            bf8_t a[4], bb[4];
            #pragma unroll
            for (int i = 0; i < 4; ++i)
                a[i] = *reinterpret_cast<bf8_t*>(&attnS[i*16 + ln15][k0 + g8]);
            #pragma unroll
            for (int n = 0; n < 4; ++n)
                bb[n] = ld8(WvT + (size_t)(wv*64 + n*16 + ln15) * CC + h*64 + k0 + g8);
            #pragma unroll
            for (int i = 0; i < 4; ++i)
                #pragma unroll
                for (int n = 0; n < 4; ++n)
                    accT[i][n] = __builtin_amdgcn_mfma_f32_16x16x32_bf16(a[i], bb[n], accT[i][n], 0,0,0);
        }
        u16* Tp = TgT + (size_t)(b*2 + dir) * CC * CC;
        const float* gp = gate + b * 256 + h * 64;
        #pragma unroll
        for (int i = 0; i < 4; ++i) {
            #pragma unroll
            for (int n = 0; n < 4; ++n) {
                int c = wv*64 + n*16 + ln15;
                u16 pk[4];
                #pragma unroll
                for (int r = 0; r < 4; ++r) {
                    int cv = i*16 + gq*4 + r;
                    pk[r] = f2bf(accT[i][n][r] * gp[cv]);
                }
                uint2 w;
                w.x = (u32)pk[0] | ((u32)pk[1] << 16);
                w.y = (u32)pk[2] | ((u32)pk[3] << 16);
                *reinterpret_cast<uint2*>(&Tp[(size_t)c * CC + h*64 + i*16 + gq*4]) = w;
            }
        }
    }
}

// ---------------- K4: E = Wproj · (g ⊙ T)  via T^T storage ----------------
// grid: 128 = b x dir x mq(64-row block), block 256
__global__ __launch_bounds__(256) void k4(const u16* __restrict__ w16,
    const u16* __restrict__ TgT, u16* __restrict__ E)
{
    const int tid = threadIdx.x, lane = tid & 63, wv = tid >> 6;
    const int ln15 = lane & 15, gq = lane >> 4, g8 = gq * 8;
    const int id = blockIdx.x;
    const int mq = id & 3, dir = (id >> 2) & 1, b = id >> 3;
    const u16* Wp = w16 + (size_t)(4 + dir) * 65536;        // dir0: wprojA, dir1: wprojB
    const u16* Tp = TgT + (size_t)(b*2 + dir) * CC * CC;
    u16* Ep = E + (size_t)(b*2 + dir) * CC * CC;
    f4_t acc[4][4];
    #pragma unroll
    for (int i=0;i<4;++i) { acc[i][0]=(f4_t){0,0,0,0}; acc[i][1]=(f4_t){0,0,0,0}; acc[i][2]=(f4_t){0,0,0,0}; acc[i][3]=(f4_t){0,0,0,0}; }
    for (int k0 = 0; k0 < 256; k0 += 32) {
        bf8_t a[4], bb[4];
        #pragma unroll
        for (int i = 0; i < 4; ++i)
            a[i] = ld8(Wp + (size_t)(mq*64 + i*16 + ln15) * CC + k0 + g8);
        #pragma unroll
        for (int n = 0; n < 4; ++n)
            bb[n] = ld8(Tp + (size_t)(wv*64 + n*16 + ln15) * CC + k0 + g8);
        #pragma unroll
        for (int i = 0; i < 4; ++i)
            #pragma unroll
            for (int n = 0; n < 4; ++n)
                acc[i][n] = __builtin_amdgcn_mfma_f32_16x16x32_bf16(a[i], bb[n], acc[i][n], 0,0,0);
    }
    #pragma unroll
    for (int i = 0; i < 4; ++i)
        #pragma unroll
        for (int n = 0; n < 4; ++n)
            #pragma unroll
            for (int r = 0; r < 4; ++r)
                Ep[(size_t)(mq*64 + i*16 + gq*4 + r) * CC + wv*64 + n*16 + ln15] = f2bf(acc[i][n][r]);
}

// ---------------- K5: out = X_res + E · X_kv (fp32 I/O) ----------------
// grid: 1024 = b x dir x 32 n-tiles(128), block 512 (8 waves, wave tile 64x64)
__global__ __launch_bounds__(512) void k5(const float* __restrict__ A, const float* __restrict__ B,
    const u16* __restrict__ E, float* __restrict__ out)
{
    const int tid = threadIdx.x, lane = tid & 63, wv = tid >> 6;
    const int ln15 = lane & 15, gq = lane >> 4, g8 = gq * 8;
    const int id = blockIdx.x;
    const int nt = id & 31, dir = (id >> 5) & 1, b = id >> 6;
    const u16* Ep = E + (size_t)(b*2 + dir) * CC * CC;
    const float* X = (dir ? A : B) + (size_t)b * CC * HWN;   // kv source
    const float* R = (dir ? B : A) + (size_t)b * CC * HWN;   // residual
    float* Op = out + (size_t)dir * ((size_t)BB*CC*HWN) + (size_t)b * CC * HWN;
    const int n0 = nt * 128;

    __shared__ alignas(16) u16 lE[256][72];
    __shared__ alignas(16) u16 lX[128][72];   // X^T tile: [n][c], c contiguous

    const int wm = wv >> 1, wn = wv & 1;
    f4_t acc[4][4];
    #pragma unroll
    for (int i=0;i<4;++i) { acc[i][0]=(f4_t){0,0,0,0}; acc[i][1]=(f4_t){0,0,0,0}; acc[i][2]=(f4_t){0,0,0,0}; acc[i][3]=(f4_t){0,0,0,0}; }

    const int xc0 = (tid >> 4) * 2;        // 0..62  (2 channel rows per thread)
    const int xn0 = (tid & 15) * 8;        // 0..120 (8 spatial cols per thread)
    const int l15 = tid & 15;              // per-lane rotation amount

    for (int k0 = 0; k0 < 256; k0 += 64) {
        // stage E chunk [256][64] (bf16, row-major K-contiguous)
        #pragma unroll
        for (int m = 0; m < 4; ++m) {
            int idx = m * 512 + tid;
            int row = idx >> 3, cc8 = (idx & 7) * 8;
            *reinterpret_cast<bf8_t*>(&lE[row][cc8]) = ld8(Ep + (size_t)row * CC + k0 + cc8);
        }
        // stage X chunk transposed. Source-matched per-row rotation:
        // load slot p holds column m=(p+l15)&7 of this lane's 8-col window;
        // store slot p writes row xn0+m. Store banks = 4*m + (xc0>>1): 8 banks
        // per 16-lane group, 2 lanes/bank = conflict-free.
        const float* px0 = X + (size_t)(k0 + xc0    ) * HWN + n0 + xn0;
        const float* px1 = X + (size_t)(k0 + xc0 + 1) * HWN + n0 + xn0;
        float v0r[8], v1r[8];
        #pragma unroll
        for (int p = 0; p < 8; ++p) {
            int m = (p + l15) & 7;
            v0r[p] = px0[m];
            v1r[p] = px1[m];
        }
        #pragma unroll
        for (int p = 0; p < 8; ++p) {
            int m = (p + l15) & 7;
            *reinterpret_cast<u32*>(&lX[xn0 + m][xc0]) = pk2(v0r[p], v1r[p]);
        }
        __syncthreads();
        #pragma unroll
        for (int ks = 0; ks < 2; ++ks) {
            bf8_t a[4], bx[4];
            #pragma unroll
            for (int i = 0; i < 4; ++i)
                a[i] = *reinterpret_cast<bf8_t*>(&lE[wm*64 + i*16 + ln15][ks*32 + g8]);
            #pragma unroll
            for (int n = 0; n < 4; ++n)
                bx[n] = *reinterpret_cast<bf8_t*>(&lX[wn*64 + n*16 + ln15][ks*32 + g8]);
            #pragma unroll
            for (int i = 0; i < 4; ++i)
                #pragma unroll
                for (int n = 0; n < 4; ++n)
                    acc[i][n] = __builtin_amdgcn_mfma_f32_16x16x32_bf16(a[i], bx[n], acc[i][n], 0,0,0);
        }
        __syncthreads();
    }
    #pragma unroll
    for (int i = 0; i < 4; ++i) {
        #pragma unroll
        for (int r = 0; r < 4; ++r) {
            int o = wm*64 + i*16 + gq*4 + r;
            #pragma unroll
            for (int n = 0; n < 4; ++n) {
                int nn = n0 + wn*64 + n*16 + ln15;
                Op[(size_t)o * HWN + nn] = acc[i][n][r] + R[(size_t)o * HWN + nn];
            }
        }
    }
}

extern "C" void kernel_launch(void* const* d_in, const int* in_sizes, int n_in,
                              void* d_out, int out_size, void* d_ws, size_t ws_size,
                              hipStream_t stream)
{
    const float* A      = (const float*)d_in[0];
    const float* B      = (const float*)d_in[1];
    const float* wqA    = (const float*)d_in[2];
    const float* wkA    = (const float*)d_in[3];
    const float* wvA    = (const float*)d_in[4];
    const float* wqB    = (const float*)d_in[5];
    const float* wkB    = (const float*)d_in[6];
    const float* wvB    = (const float*)d_in[7];
    const float* wg1    = (const float*)d_in[8];
    const float* bg1    = (const float*)d_in[9];
    const float* wg2    = (const float*)d_in[10];
    const float* bg2    = (const float*)d_in[11];
    const float* wprojA = (const float*)d_in[12];
    const float* wprojB = (const float*)d_in[13];
    float* out = (float*)d_out;
    char* ws = (char*)d_ws;

    float* Gpart  = (float*)(ws);                 // [2][16][256][256] f32 = 8 MB
    u16*   Gb     = (u16*)(ws + 8388608);         // [16][256][256] bf16
    u16*   GTb    = (u16*)(ws + 10485760);        // [16][256][256] bf16
    float* pooled = (float*)(ws + 12582912);      // [16][512] f32
    float* gate   = (float*)(ws + 12615680);      // [16][256] f32
    u16*   WvAT   = (u16*)(ws + 12632064);        // [256][256] bf16
    u16*   WvBT   = (u16*)(ws + 12763136);        // [256][256] bf16
    u16*   TgT    = (u16*)(ws + 12894208);        // [16][2][256][256] bf16
    u16*   E      = (u16*)(ws + 17088512);        // [16][2][256][256] bf16
    u16*   w16    = (u16*)(ws + 21282816);        // 6 x [256][256] bf16 weight copies
    if (ws_size < 22069248) return;

    k1<<<256, 512, 0, stream>>>(A, B, Gpart, pooled);
    k2<<<88, 256, 0, stream>>>(Gpart, pooled, wg1, bg1, wg2, bg2, wvA, wvB,
                               wqA, wqB, wkA, wkB, wprojA, wprojB,
                               Gb, GTb, gate, WvAT, WvBT, w16);
    k3<<<128, 256, 0, stream>>>(w16, Gb, GTb, WvAT, WvBT, gate, TgT);
    k4<<<128, 256, 0, stream>>>(w16, TgT, E);
    k5<<<1024, 512, 0, stream>>>(A, B, E, out);
}